// Round 1
// baseline (482.855 us; speedup 1.0000x reference)
//
#include <hip/hip_runtime.h>
#include <math.h>

#define N1 2000
#define N2 2000
#define NT 4000
#define D  63
#define E  64
#define H  8
#define KNN 5

// ---------------------------------------------------------------- k_sq
__global__ void k_sq(const float* __restrict__ X, float* __restrict__ sq) {
    int i = blockIdx.x * blockDim.x + threadIdx.x;
    if (i < N1) {
        float s = 0.f;
        for (int d = 0; d < D; ++d) { float v = X[i * D + d]; s += v * v; }
        sq[i] = s;
    }
}

// ---------------------------------------------------------------- k_d2
// 16x16 output tile per block (256 threads, 1 thread/pair), K=63 from LDS.
__global__ __launch_bounds__(256) void k_d2(const float* __restrict__ X,
                                            const float* __restrict__ sq,
                                            float* __restrict__ d2) {
    __shared__ float Xi[16][D + 2];   // pad to 65 -> conflict-free
    __shared__ float Xj[16][D + 2];
    int i0 = blockIdx.y * 16, j0 = blockIdx.x * 16;
    int tid = threadIdx.x;
    for (int t = tid; t < 16 * D; t += 256) {
        int r = t / D, c = t % D;
        Xi[r][c] = X[(i0 + r) * D + c];
        Xj[r][c] = X[(j0 + r) * D + c];
    }
    __syncthreads();
    int tx = tid & 15, ty = tid >> 4;
    float acc = 0.f;
    #pragma unroll
    for (int d = 0; d < D; ++d) acc += Xi[ty][d] * Xj[tx][d];
    int i = i0 + ty, j = j0 + tx;
    float v = sq[i] + sq[j] - 2.f * acc;
    if (i == j) v = __builtin_inff();
    d2[i * N1 + j] = v;
}

// ---------------------------------------------------------------- k_top5
__device__ __forceinline__ bool dless(float d1, int i1, float d2v, int i2) {
    return d1 < d2v || (d1 == d2v && i1 < i2);   // stable top_k tie-break
}

__device__ __forceinline__ void ins5(float bd[KNN], int bi[KNN], float d, int j) {
    if (dless(d, j, bd[KNN - 1], bi[KNN - 1])) {
        bd[KNN - 1] = d; bi[KNN - 1] = j;
        #pragma unroll
        for (int s = KNN - 1; s > 0; --s) {
            if (dless(bd[s], bi[s], bd[s - 1], bi[s - 1])) {
                float td = bd[s]; bd[s] = bd[s - 1]; bd[s - 1] = td;
                int ti = bi[s]; bi[s] = bi[s - 1]; bi[s - 1] = ti;
            }
        }
    }
}

__global__ __launch_bounds__(256) void k_top5(const float* __restrict__ d2,
                                              const float* __restrict__ lmY,
                                              float* __restrict__ ypred,
                                              int* __restrict__ idx) {
    __shared__ float sd[256 * KNN];
    __shared__ int   si[256 * KNN];
    int i = blockIdx.x;
    int tid = threadIdx.x;
    float bd[KNN]; int bi[KNN];
    #pragma unroll
    for (int s = 0; s < KNN; ++s) { bd[s] = __builtin_inff(); bi[s] = 0x7fffffff; }
    for (int j = tid; j < N1; j += 256) ins5(bd, bi, d2[i * N1 + j], j);
    #pragma unroll
    for (int s = 0; s < KNN; ++s) { sd[tid * KNN + s] = bd[s]; si[tid * KNN + s] = bi[s]; }
    __syncthreads();
    // stage 1: 32 threads merge 8 lists each (reads done before write barrier)
    if (tid < 32) {
        #pragma unroll
        for (int s = 0; s < KNN; ++s) { bd[s] = __builtin_inff(); bi[s] = 0x7fffffff; }
        for (int t = tid * 8; t < tid * 8 + 8; ++t)
            for (int s = 0; s < KNN; ++s) ins5(bd, bi, sd[t * KNN + s], si[t * KNN + s]);
    }
    __syncthreads();
    if (tid < 32) {
        #pragma unroll
        for (int s = 0; s < KNN; ++s) { sd[tid * KNN + s] = bd[s]; si[tid * KNN + s] = bi[s]; }
    }
    __syncthreads();
    if (tid == 0) {
        #pragma unroll
        for (int s = 0; s < KNN; ++s) { bd[s] = __builtin_inff(); bi[s] = 0x7fffffff; }
        for (int t = 0; t < 32; ++t)
            for (int s = 0; s < KNN; ++s) ins5(bd, bi, sd[t * KNN + s], si[t * KNN + s]);
        float y0 = 0.f, y1 = 0.f;
        #pragma unroll
        for (int s = 0; s < KNN; ++s) {
            int j = bi[s];
            y0 += lmY[j * 2];
            y1 += lmY[j * 2 + 1];
            idx[i * KNN + s] = j;
        }
        ypred[i * 2]     = y0 * 0.2f;
        ypred[i * 2 + 1] = y1 * 0.2f;
    }
}

// ---------------------------------------------------------------- k_fillT
// adj_teacher base pattern: cross blocks = 1, diagonal blocks = 0.
__global__ void k_fillT(float* __restrict__ adjT) {
    int t = blockIdx.x * blockDim.x + threadIdx.x;   // float4 index
    if (t < NT * NT / 4) {
        int r = (t * 4) / NT;
        int c = (t * 4) % NT;
        float v = ((r < N1) != (c < N1)) ? 1.f : 0.f;
        float4 o = {v, v, v, v};
        ((float4*)adjT)[t] = o;
    }
}

__global__ void k_scatter(const int* __restrict__ idx, float* __restrict__ adjT) {
    int t = blockIdx.x * blockDim.x + threadIdx.x;
    if (t < N1 * KNN) {
        int i = t / KNN;
        adjT[i * NT + idx[t]] = 1.f;
    }
}

// ---------------------------------------------------------------- k_emb
// e[n,i] = b[i] + sum_d feats[n,d] * W_emb[i,d]   (feats[:,63] = delay)
__global__ __launch_bounds__(64) void k_emb(const float* __restrict__ lmX,
                                            const float* __restrict__ tgX,
                                            const float* __restrict__ lmD,
                                            const float* __restrict__ tgD,
                                            const float* __restrict__ W,
                                            const float* __restrict__ b,
                                            float* __restrict__ e) {
    __shared__ float f[E];
    int n = blockIdx.x;
    int t = threadIdx.x;
    if (t < D)  f[t] = (n < N1) ? lmX[n * D + t] : tgX[(n - N1) * D + t];
    if (t == D) f[t] = (n < N1) ? lmD[n] : tgD[n - N1];
    __syncthreads();
    float s = b[t];
    #pragma unroll
    for (int d = 0; d < E; ++d) s += f[d] * W[t * E + d];
    e[n * E + t] = s;
}

// ---------------------------------------------------------------- k_norms
// ina[n,h] = 1/||e[n,:]*w1[:,h]||, inb with w2
__global__ void k_norms(const float* __restrict__ e,
                        const float* __restrict__ w1,
                        const float* __restrict__ w2,
                        float* __restrict__ ina, float* __restrict__ inb) {
    int n = blockIdx.x;
    int t = threadIdx.x;     // 16 threads: 0..7 -> ina, 8..15 -> inb
    int h = t & 7;
    const float* w = (t < 8) ? w1 : w2;
    float s = 0.f;
    for (int k = 0; k < E; ++k) {
        float v = e[n * E + k] * w[k * H + h];
        s += v * v;
    }
    float r = 1.0f / sqrtf(s);
    if (t < 8) ina[n * H + h] = r; else inb[n * H + h] = r;
}

// ---------------------------------------------------------------- k_adj
// 32x32 output tile per block; per thread 2x2 pairs x 8 head accumulators.
// dot[n,m,h] = sum_e e_n[e]*e_m[e]*W[e,h],  W = w1 .* w2
__global__ __launch_bounds__(256) void k_adj(const float* __restrict__ eg,
                                             const float* __restrict__ ina,
                                             const float* __restrict__ inb,
                                             const float* __restrict__ w1,
                                             const float* __restrict__ w2,
                                             float* __restrict__ adj) {
    __shared__ float eN[E][34];   // transposed, padded (2-way conflict = free)
    __shared__ float eM[E][34];
    __shared__ float Ws[E][H];
    __shared__ float sA[32][H];
    __shared__ float sB[32][H];
    int tid = threadIdx.x;
    int n0 = blockIdx.y * 32, m0 = blockIdx.x * 32;
    for (int t = tid; t < 32 * E; t += 256) {
        int r = t >> 6, c = t & 63;
        eN[c][r] = eg[(n0 + r) * E + c];
        eM[c][r] = eg[(m0 + r) * E + c];
    }
    for (int t = tid; t < E * H; t += 256) Ws[t >> 3][t & 7] = w1[t] * w2[t];
    {
        int r = tid >> 3, h = tid & 7;
        sA[r][h] = ina[(n0 + r) * H + h];
        sB[r][h] = inb[(m0 + r) * H + h];
    }
    __syncthreads();

    int tx = tid & 15, ty = tid >> 4;
    float acc[2][2][H];
    #pragma unroll
    for (int i = 0; i < 2; ++i)
        #pragma unroll
        for (int j = 0; j < 2; ++j)
            #pragma unroll
            for (int h = 0; h < H; ++h) acc[i][j][h] = 0.f;

    #pragma unroll 8
    for (int k = 0; k < E; ++k) {
        float2 av = *(const float2*)&eN[k][2 * ty];
        float2 bv = *(const float2*)&eM[k][2 * tx];
        float4 wa = *(const float4*)&Ws[k][0];
        float4 wb = *(const float4*)&Ws[k][4];
        float p00 = av.x * bv.x, p01 = av.x * bv.y;
        float p10 = av.y * bv.x, p11 = av.y * bv.y;
        float wh[H] = {wa.x, wa.y, wa.z, wa.w, wb.x, wb.y, wb.z, wb.w};
        #pragma unroll
        for (int h = 0; h < H; ++h) {
            acc[0][0][h] += p00 * wh[h];
            acc[0][1][h] += p01 * wh[h];
            acc[1][0][h] += p10 * wh[h];
            acc[1][1][h] += p11 * wh[h];
        }
    }

    #pragma unroll
    for (int i = 0; i < 2; ++i) {
        int n = 2 * ty + i;
        #pragma unroll
        for (int j = 0; j < 2; ++j) {
            int m = 2 * tx + j;
            float s = 0.f;
            #pragma unroll
            for (int h = 0; h < H; ++h) {
                float sim = acc[i][j][h] * sA[n][h] * sB[m][h];
                float t = __expf(-sim);
                s += __builtin_amdgcn_rcpf(1.0f + t);
            }
            adj[(n0 + n) * NT + (m0 + m)] = s * 0.125f;
        }
    }
}

// ---------------------------------------------------------------- launch
extern "C" void kernel_launch(void* const* d_in, const int* in_sizes, int n_in,
                              void* d_out, int out_size, void* d_ws, size_t ws_size,
                              hipStream_t stream) {
    const float* lmX  = (const float*)d_in[0];
    const float* lmY  = (const float*)d_in[1];
    const float* tgX  = (const float*)d_in[2];
    // d_in[3] (tg_Y) unused by the reference outputs
    const float* lmD  = (const float*)d_in[4];
    const float* tgD  = (const float*)d_in[5];
    const float* Wemb = (const float*)d_in[6];
    const float* bemb = (const float*)d_in[7];
    const float* w1   = (const float*)d_in[8];
    const float* w2   = (const float*)d_in[9];

    float* out   = (float*)d_out;
    float* ypred = out;                         // [N1,2] = 4000
    float* adj   = out + 4000;                  // [NT,NT] = 16M
    float* adjT  = out + 4000 + 16000000;       // [NT,NT] = 16M

    char*  ws   = (char*)d_ws;
    float* e_buf = (float*)ws;                   // 4000*64*4   = 1,024,000 B
    float* ina   = (float*)(ws + 1024000);       // 4000*8*4    =   128,000 B
    float* inb   = (float*)(ws + 1152000);       // 4000*8*4    =   128,000 B
    float* sq    = (float*)(ws + 1280000);       // 2000*4      =     8,000 B
    int*   idx   = (int*)  (ws + 1288000);       // 2000*5*4    =    40,000 B

    float* d2 = adjT;   // stage d2 in the adj_teacher region (filled later)

    k_sq<<<(N1 + 255) / 256, 256, 0, stream>>>(lmX, sq);
    dim3 g2(N1 / 16, N1 / 16);
    k_d2<<<g2, 256, 0, stream>>>(lmX, sq, d2);
    k_top5<<<N1, 256, 0, stream>>>(d2, lmY, ypred, idx);
    k_fillT<<<(NT * NT / 4 + 255) / 256, 256, 0, stream>>>(adjT);
    k_scatter<<<(N1 * KNN + 255) / 256, 256, 0, stream>>>(idx, adjT);
    k_emb<<<NT, 64, 0, stream>>>(lmX, tgX, lmD, tgD, Wemb, bemb, e_buf);
    k_norms<<<NT, 16, 0, stream>>>(e_buf, w1, w2, ina, inb);
    dim3 ga(NT / 32, NT / 32);
    k_adj<<<ga, 256, 0, stream>>>(e_buf, ina, inb, w1, w2, adj);
}

// Round 2
// 343.805 us; speedup vs baseline: 1.4044x; 1.4044x over previous
//
#include <hip/hip_runtime.h>
#include <math.h>

#define N1 2000
#define N2 2000
#define NT 4000
#define D  63
#define E  64
#define H  8
#define KNN 5
#define NPAD 4032   // 63 blocks of 64 rows

typedef short bf16x8 __attribute__((ext_vector_type(8)));
typedef float f32x4  __attribute__((ext_vector_type(4)));

__device__ __forceinline__ unsigned short f2bf(float x) {
    unsigned u = __float_as_uint(x);
    u = (u + 0x7fffu + ((u >> 16) & 1u)) >> 16;   // RN-even
    return (unsigned short)u;
}

// ---------------------------------------------------------------- k_sq
__global__ void k_sq(const float* __restrict__ X, float* __restrict__ sq) {
    int i = blockIdx.x * blockDim.x + threadIdx.x;
    if (i < N1) {
        float s = 0.f;
        for (int d = 0; d < D; ++d) { float v = X[i * D + d]; s += v * v; }
        sq[i] = s;
    }
}

// ---------------------------------------------------------------- k_d2
__global__ __launch_bounds__(256) void k_d2(const float* __restrict__ X,
                                            const float* __restrict__ sq,
                                            float* __restrict__ d2) {
    __shared__ float Xi[16][D + 2];
    __shared__ float Xj[16][D + 2];
    int i0 = blockIdx.y * 16, j0 = blockIdx.x * 16;
    int tid = threadIdx.x;
    for (int t = tid; t < 16 * D; t += 256) {
        int r = t / D, c = t % D;
        Xi[r][c] = X[(i0 + r) * D + c];
        Xj[r][c] = X[(j0 + r) * D + c];
    }
    __syncthreads();
    int tx = tid & 15, ty = tid >> 4;
    float acc = 0.f;
    #pragma unroll
    for (int d = 0; d < D; ++d) acc += Xi[ty][d] * Xj[tx][d];
    int i = i0 + ty, j = j0 + tx;
    float v = sq[i] + sq[j] - 2.f * acc;
    if (i == j) v = __builtin_inff();
    d2[i * N1 + j] = v;
}

// ---------------------------------------------------------------- k_top5
__device__ __forceinline__ bool dless(float d1, int i1, float d2v, int i2) {
    return d1 < d2v || (d1 == d2v && i1 < i2);
}

__device__ __forceinline__ void ins5(float bd[KNN], int bi[KNN], float d, int j) {
    if (dless(d, j, bd[KNN - 1], bi[KNN - 1])) {
        bd[KNN - 1] = d; bi[KNN - 1] = j;
        #pragma unroll
        for (int s = KNN - 1; s > 0; --s) {
            if (dless(bd[s], bi[s], bd[s - 1], bi[s - 1])) {
                float td = bd[s]; bd[s] = bd[s - 1]; bd[s - 1] = td;
                int ti = bi[s]; bi[s] = bi[s - 1]; bi[s - 1] = ti;
            }
        }
    }
}

__global__ __launch_bounds__(256) void k_top5(const float* __restrict__ d2,
                                              const float* __restrict__ lmY,
                                              float* __restrict__ ypred,
                                              int* __restrict__ idx) {
    __shared__ float sd[256 * KNN];
    __shared__ int   si[256 * KNN];
    int i = blockIdx.x;
    int tid = threadIdx.x;
    float bd[KNN]; int bi[KNN];
    #pragma unroll
    for (int s = 0; s < KNN; ++s) { bd[s] = __builtin_inff(); bi[s] = 0x7fffffff; }
    for (int j = tid; j < N1; j += 256) ins5(bd, bi, d2[i * N1 + j], j);
    #pragma unroll
    for (int s = 0; s < KNN; ++s) { sd[tid * KNN + s] = bd[s]; si[tid * KNN + s] = bi[s]; }
    __syncthreads();
    if (tid < 32) {
        #pragma unroll
        for (int s = 0; s < KNN; ++s) { bd[s] = __builtin_inff(); bi[s] = 0x7fffffff; }
        for (int t = tid * 8; t < tid * 8 + 8; ++t)
            for (int s = 0; s < KNN; ++s) ins5(bd, bi, sd[t * KNN + s], si[t * KNN + s]);
    }
    __syncthreads();
    if (tid < 32) {
        #pragma unroll
        for (int s = 0; s < KNN; ++s) { sd[tid * KNN + s] = bd[s]; si[tid * KNN + s] = bi[s]; }
    }
    __syncthreads();
    if (tid == 0) {
        #pragma unroll
        for (int s = 0; s < KNN; ++s) { bd[s] = __builtin_inff(); bi[s] = 0x7fffffff; }
        for (int t = 0; t < 32; ++t)
            for (int s = 0; s < KNN; ++s) ins5(bd, bi, sd[t * KNN + s], si[t * KNN + s]);
        float y0 = 0.f, y1 = 0.f;
        #pragma unroll
        for (int s = 0; s < KNN; ++s) {
            int j = bi[s];
            y0 += lmY[j * 2];
            y1 += lmY[j * 2 + 1];
            idx[i * KNN + s] = j;
        }
        ypred[i * 2]     = y0 * 0.2f;
        ypred[i * 2 + 1] = y1 * 0.2f;
    }
}

// ---------------------------------------------------------------- k_fillT
__global__ void k_fillT(float* __restrict__ adjT) {
    int t = blockIdx.x * blockDim.x + threadIdx.x;
    if (t < NT * NT / 4) {
        int r = (t * 4) / NT;
        int c = (t * 4) % NT;
        float v = ((r < N1) != (c < N1)) ? 1.f : 0.f;
        float4 o = {v, v, v, v};
        ((float4*)adjT)[t] = o;
    }
}

__global__ void k_scatter(const int* __restrict__ idx, float* __restrict__ adjT) {
    int t = blockIdx.x * blockDim.x + threadIdx.x;
    if (t < N1 * KNN) {
        int i = t / KNN;
        adjT[i * NT + idx[t]] = 1.f;
    }
}

// ---------------------------------------------------------------- k_prep
// Fused: embedding row e[n,:], per-head norms, bf16 operand tensors.
//  Abuf[n][h][e] = bf16( e * w1[e,h]*w2[e,h] )
//  Bbuf[n][e]    = bf16( e )
//  sA[n][h] = -log2(e) / ||e .* w1[:,h]||     (sign & log2e folded)
//  sB[n][h] =  1.0    / ||e .* w2[:,h]||
__global__ __launch_bounds__(64) void k_prep(const float* __restrict__ lmX,
                                             const float* __restrict__ tgX,
                                             const float* __restrict__ lmD,
                                             const float* __restrict__ tgD,
                                             const float* __restrict__ W,
                                             const float* __restrict__ bias,
                                             const float* __restrict__ w1,
                                             const float* __restrict__ w2,
                                             unsigned short* __restrict__ Abuf,
                                             unsigned short* __restrict__ Bbuf,
                                             float* __restrict__ sA,
                                             float* __restrict__ sB) {
    __shared__ float f[E];   // D+1 == 64 == E
    int n = blockIdx.x;
    int t = threadIdx.x;     // t = embedding index, one wave
    if (t < D)  f[t] = (n < N1) ? lmX[n * D + t] : tgX[(n - N1) * D + t];
    if (t == D) f[t] = (n < N1) ? lmD[n] : tgD[n - N1];
    __syncthreads();
    float s = bias[t];
    #pragma unroll
    for (int d = 0; d < E; ++d) s += f[d] * W[t * E + d];
    const float en = s;
    Bbuf[n * E + t] = f2bf(en);
    #pragma unroll
    for (int h = 0; h < H; ++h) {
        float a = en * w1[t * H + h];
        float b = en * w2[t * H + h];
        float na2 = a * a, nb2 = b * b;
        #pragma unroll
        for (int m = 32; m >= 1; m >>= 1) {
            na2 += __shfl_xor(na2, m, 64);
            nb2 += __shfl_xor(nb2, m, 64);
        }
        Abuf[(n * H + h) * E + t] = f2bf(en * w1[t * H + h] * w2[t * H + h]);
        if (t == h)     sA[n * H + h] = -1.4426950408889634f * rsqrtf(na2);
        if (t == h + 8) sB[n * H + h] = rsqrtf(nb2);
    }
}

// ---------------------------------------------------------------- k_adjm
// Block: 4 waves, tile 64(n) x 64(m). Wave w: rows n0+16w..+15, all 64 m.
// Per m-subtile (16 cols): 8 heads x 2 k-chunks MFMA 16x16x32 bf16,
// epilogue mean-of-sigmoids in registers.
__global__ __launch_bounds__(256) void k_adjm(const unsigned short* __restrict__ Abuf,
                                              const unsigned short* __restrict__ Bbuf,
                                              const float* __restrict__ sA,
                                              const float* __restrict__ sB,
                                              float* __restrict__ adj) {
    __shared__ float sBs[64 * H];
    int tid = threadIdx.x;
    int n0 = blockIdx.y * 64, m0 = blockIdx.x * 64;
    for (int t = tid; t < 64 * H; t += 256) sBs[t] = sB[m0 * H + t];

    int wave = tid >> 6, lane = tid & 63;
    int l15 = lane & 15, kq = lane >> 4;          // frag row/col, k-quad
    int nrow = n0 + wave * 16 + l15;              // A fragment row

    bf16x8 afr[H][2];
    #pragma unroll
    for (int h = 0; h < H; ++h)
        #pragma unroll
        for (int kc = 0; kc < 2; ++kc)
            afr[h][kc] = *(const bf16x8*)&Abuf[(nrow * H + h) * E + kc * 32 + kq * 8];

    // epilogue row-scales: n_e = n0+16w + kq*4 + reg  (C layout row)
    float sav[4][H];
    #pragma unroll
    for (int reg = 0; reg < 4; ++reg) {
        int ne = n0 + wave * 16 + kq * 4 + reg;
        *(f32x4*)&sav[reg][0] = *(const f32x4*)&sA[ne * H + 0];
        *(f32x4*)&sav[reg][4] = *(const f32x4*)&sA[ne * H + 4];
    }
    __syncthreads();

    #pragma unroll
    for (int mt = 0; mt < 4; ++mt) {
        int mcol = m0 + mt * 16 + l15;
        bf16x8 bfr0 = *(const bf16x8*)&Bbuf[mcol * E + kq * 8];
        bf16x8 bfr1 = *(const bf16x8*)&Bbuf[mcol * E + 32 + kq * 8];

        f32x4 acc[H];
        #pragma unroll
        for (int h = 0; h < H; ++h) {
            acc[h] = (f32x4){0.f, 0.f, 0.f, 0.f};
            acc[h] = __builtin_amdgcn_mfma_f32_16x16x32_bf16(afr[h][0], bfr0, acc[h], 0, 0, 0);
            acc[h] = __builtin_amdgcn_mfma_f32_16x16x32_bf16(afr[h][1], bfr1, acc[h], 0, 0, 0);
        }

        float sbv[H];
        *(f32x4*)&sbv[0] = *(const f32x4*)&sBs[(mt * 16 + l15) * H + 0];
        *(f32x4*)&sbv[4] = *(const f32x4*)&sBs[(mt * 16 + l15) * H + 4];

        bool mok = (mcol < NT);
        #pragma unroll
        for (int reg = 0; reg < 4; ++reg) {
            int ne = n0 + wave * 16 + kq * 4 + reg;
            float sum = 0.f;
            #pragma unroll
            for (int h = 0; h < H; ++h) {
                float arg = acc[h][reg] * sav[reg][h] * sbv[h];  // = -sim*log2e
                float tv = exp2f(arg);                            // exp(-sim)
                sum += __builtin_amdgcn_rcpf(1.0f + tv);
            }
            if (mok && ne < NT) adj[ne * NT + mcol] = sum * 0.125f;
        }
    }
}

// ---------------------------------------------------------------- launch
extern "C" void kernel_launch(void* const* d_in, const int* in_sizes, int n_in,
                              void* d_out, int out_size, void* d_ws, size_t ws_size,
                              hipStream_t stream) {
    const float* lmX  = (const float*)d_in[0];
    const float* lmY  = (const float*)d_in[1];
    const float* tgX  = (const float*)d_in[2];
    const float* lmD  = (const float*)d_in[4];
    const float* tgD  = (const float*)d_in[5];
    const float* Wemb = (const float*)d_in[6];
    const float* bemb = (const float*)d_in[7];
    const float* w1   = (const float*)d_in[8];
    const float* w2   = (const float*)d_in[9];

    float* out   = (float*)d_out;
    float* ypred = out;                          // [N1,2]
    float* adj   = out + 4000;                   // [NT,NT]
    float* adjT  = out + 4000 + 16000000;        // [NT,NT]

    // small scratch in ws
    char* ws  = (char*)d_ws;
    float* sq = (float*)ws;                      //   8,000 B
    int*   idx = (int*)(ws + 8000);              //  40,000 B

    // d2 staged in adj region (consumed by k_top5 before k_adjm writes adj)
    float* d2 = adj;

    // MFMA operands staged in adjT region (overwritten by k_fillT afterwards)
    char* tz = (char*)adjT;
    unsigned short* Abuf = (unsigned short*)tz;                    // NPAD*8*64*2 = 4,128,768
    unsigned short* Bbuf = (unsigned short*)(tz + 4128768);        // NPAD*64*2   =   516,096
    float*          sA   = (float*)(tz + 4128768 + 516096);        // NPAD*8*4    =   129,024
    float*          sB   = (float*)(tz + 4128768 + 516096 + 129024);

    k_sq<<<(N1 + 255) / 256, 256, 0, stream>>>(lmX, sq);
    dim3 g2(N1 / 16, N1 / 16);
    k_d2<<<g2, 256, 0, stream>>>(lmX, sq, d2);
    k_top5<<<N1, 256, 0, stream>>>(d2, lmY, ypred, idx);
    k_prep<<<NT, 64, 0, stream>>>(lmX, tgX, lmD, tgD, Wemb, bemb, w1, w2,
                                  Abuf, Bbuf, sA, sB);
    dim3 ga(NPAD / 64, NPAD / 64);
    k_adjm<<<ga, 256, 0, stream>>>(Abuf, Bbuf, sA, sB, adj);
    k_fillT<<<(NT * NT / 4 + 255) / 256, 256, 0, stream>>>(adjT);
    k_scatter<<<(N1 * KNN + 255) / 256, 256, 0, stream>>>(idx, adjT);
}

// Round 3
// 312.720 us; speedup vs baseline: 1.5440x; 1.0994x over previous
//
#include <hip/hip_runtime.h>
#include <math.h>

#define N1 2000
#define N2 2000
#define NT 4000
#define D  63
#define E  64
#define H  8
#define KNN 5
#define NPAD 4032   // n padded: 63 blocks of 64
#define MPAD 4096   // m padded: 16 blocks of 256

typedef short bf16x8 __attribute__((ext_vector_type(8)));
typedef float f32x4  __attribute__((ext_vector_type(4)));

__device__ __forceinline__ unsigned short f2bf(float x) {
    unsigned u = __float_as_uint(x);
    u = (u + 0x7fffu + ((u >> 16) & 1u)) >> 16;   // RN-even
    return (unsigned short)u;
}

// ---------------------------------------------------------------- k_sq
__global__ void k_sq(const float* __restrict__ X, float* __restrict__ sq) {
    int i = blockIdx.x * blockDim.x + threadIdx.x;
    if (i < N1) {
        float s = 0.f;
        for (int d = 0; d < D; ++d) { float v = X[i * D + d]; s += v * v; }
        sq[i] = s;
    }
}

// ---------------------------------------------------------------- k_d2
__global__ __launch_bounds__(256) void k_d2(const float* __restrict__ X,
                                            const float* __restrict__ sq,
                                            float* __restrict__ d2) {
    __shared__ float Xi[16][D + 2];
    __shared__ float Xj[16][D + 2];
    int i0 = blockIdx.y * 16, j0 = blockIdx.x * 16;
    int tid = threadIdx.x;
    for (int t = tid; t < 16 * D; t += 256) {
        int r = t / D, c = t % D;
        Xi[r][c] = X[(i0 + r) * D + c];
        Xj[r][c] = X[(j0 + r) * D + c];
    }
    __syncthreads();
    int tx = tid & 15, ty = tid >> 4;
    float acc = 0.f;
    #pragma unroll
    for (int d = 0; d < D; ++d) acc += Xi[ty][d] * Xj[tx][d];
    int i = i0 + ty, j = j0 + tx;
    float v = sq[i] + sq[j] - 2.f * acc;
    if (i == j) v = __builtin_inff();
    d2[i * N1 + j] = v;
}

// ---------------------------------------------------------------- k_top5
__device__ __forceinline__ bool dless(float d1, int i1, float d2v, int i2) {
    return d1 < d2v || (d1 == d2v && i1 < i2);
}

__device__ __forceinline__ void ins5(float bd[KNN], int bi[KNN], float d, int j) {
    if (dless(d, j, bd[KNN - 1], bi[KNN - 1])) {
        bd[KNN - 1] = d; bi[KNN - 1] = j;
        #pragma unroll
        for (int s = KNN - 1; s > 0; --s) {
            if (dless(bd[s], bi[s], bd[s - 1], bi[s - 1])) {
                float td = bd[s]; bd[s] = bd[s - 1]; bd[s - 1] = td;
                int ti = bi[s]; bi[s] = bi[s - 1]; bi[s - 1] = ti;
            }
        }
    }
}

__global__ __launch_bounds__(256) void k_top5(const float* __restrict__ d2,
                                              const float* __restrict__ lmY,
                                              float* __restrict__ ypred,
                                              int* __restrict__ idx) {
    __shared__ float sd[256 * KNN];
    __shared__ int   si[256 * KNN];
    int i = blockIdx.x;
    int tid = threadIdx.x;
    float bd[KNN]; int bi[KNN];
    #pragma unroll
    for (int s = 0; s < KNN; ++s) { bd[s] = __builtin_inff(); bi[s] = 0x7fffffff; }
    for (int j = tid; j < N1; j += 256) ins5(bd, bi, d2[i * N1 + j], j);
    #pragma unroll
    for (int s = 0; s < KNN; ++s) { sd[tid * KNN + s] = bd[s]; si[tid * KNN + s] = bi[s]; }
    __syncthreads();
    if (tid < 32) {
        #pragma unroll
        for (int s = 0; s < KNN; ++s) { bd[s] = __builtin_inff(); bi[s] = 0x7fffffff; }
        for (int t = tid * 8; t < tid * 8 + 8; ++t)
            for (int s = 0; s < KNN; ++s) ins5(bd, bi, sd[t * KNN + s], si[t * KNN + s]);
    }
    __syncthreads();
    if (tid < 32) {
        #pragma unroll
        for (int s = 0; s < KNN; ++s) { sd[tid * KNN + s] = bd[s]; si[tid * KNN + s] = bi[s]; }
    }
    __syncthreads();
    if (tid == 0) {
        #pragma unroll
        for (int s = 0; s < KNN; ++s) { bd[s] = __builtin_inff(); bi[s] = 0x7fffffff; }
        for (int t = 0; t < 32; ++t)
            for (int s = 0; s < KNN; ++s) ins5(bd, bi, sd[t * KNN + s], si[t * KNN + s]);
        float y0 = 0.f, y1 = 0.f;
        #pragma unroll
        for (int s = 0; s < KNN; ++s) {
            int j = bi[s];
            y0 += lmY[j * 2];
            y1 += lmY[j * 2 + 1];
            idx[i * KNN + s] = j;
        }
        ypred[i * 2]     = y0 * 0.2f;
        ypred[i * 2 + 1] = y1 * 0.2f;
    }
}

// ---------------------------------------------------------------- k_fillT
__global__ void k_fillT(float* __restrict__ adjT) {
    int t = blockIdx.x * blockDim.x + threadIdx.x;
    if (t < NT * NT / 4) {
        int r = (t * 4) / NT;
        int c = (t * 4) % NT;
        float v = ((r < N1) != (c < N1)) ? 1.f : 0.f;
        float4 o = {v, v, v, v};
        ((float4*)adjT)[t] = o;
    }
}

__global__ void k_scatter(const int* __restrict__ idx, float* __restrict__ adjT) {
    int t = blockIdx.x * blockDim.x + threadIdx.x;
    if (t < N1 * KNN) {
        int i = t / KNN;
        adjT[i * NT + idx[t]] = 1.f;
    }
}

// ---------------------------------------------------------------- k_prep
// Fused embedding + norms + MFMA operand build.
//  AL: A fragments in lane-swizzled chunk layout. chunk = ((n>>4)*8+h)*2+kc,
//      within chunk lane=(kq*16 + n&15) holds 8 bf16 of
//      A[n][e=kc*32+kq*8+j] = e_n[e]*w1[e,h]*w2[e,h] * (-log2e)/||e_n.*w1[:,h]||
//  Bbuf[m][e] = bf16(e_m[e])        (row-major)
//  sB[m][h]   = 1/||e_m .* w2[:,h]||
__global__ __launch_bounds__(64) void k_prep(const float* __restrict__ lmX,
                                             const float* __restrict__ tgX,
                                             const float* __restrict__ lmD,
                                             const float* __restrict__ tgD,
                                             const float* __restrict__ W,
                                             const float* __restrict__ bias,
                                             const float* __restrict__ w1,
                                             const float* __restrict__ w2,
                                             unsigned short* __restrict__ AL,
                                             unsigned short* __restrict__ Bbuf,
                                             float* __restrict__ sB) {
    __shared__ float f[E];   // D+1 == 64 == E
    int n = blockIdx.x;
    int t = threadIdx.x;     // t = embedding index e, one wave
    if (t < D)  f[t] = (n < N1) ? lmX[n * D + t] : tgX[(n - N1) * D + t];
    if (t == D) f[t] = (n < N1) ? lmD[n] : tgD[n - N1];
    __syncthreads();
    float s = bias[t];
    #pragma unroll
    for (int d = 0; d < E; ++d) s += f[d] * W[t * E + d];
    const float en = s;
    Bbuf[n * E + t] = f2bf(en);

    int kc = t >> 5, kq = (t >> 3) & 3, j = t & 7;
    int lane = kq * 16 + (n & 15);
    int nb = n >> 4;
    #pragma unroll
    for (int h = 0; h < H; ++h) {
        float a = en * w1[t * H + h];
        float b = en * w2[t * H + h];
        float na2 = a * a, nb2 = b * b;
        #pragma unroll
        for (int m = 32; m >= 1; m >>= 1) {
            na2 += __shfl_xor(na2, m, 64);
            nb2 += __shfl_xor(nb2, m, 64);
        }
        float val = a * w2[t * H + h] * (-1.4426950408889634f) * rsqrtf(na2);
        AL[(((nb * 8 + h) << 1) + kc) * 512 + lane * 8 + j] = f2bf(val);
        if (t == h) sB[n * H + h] = rsqrtf(nb2);
    }
}

// ---------------------------------------------------------------- k_adjm
// Block: 4 waves, tile 64(n) x 256(m). B tile + sB staged in LDS (coalesced),
// A frags (8 heads x 2 k-chunks) in registers, reused over 16 m-subtiles.
__global__ __launch_bounds__(256) void k_adjm(const unsigned short* __restrict__ AL,
                                              const unsigned short* __restrict__ Bbuf,
                                              const float* __restrict__ sB,
                                              float* __restrict__ adj) {
    __shared__ unsigned short Bt[256][72];   // pad 64->72: conflict-free b128
    __shared__ float sBt[256][8];
    int tid = threadIdx.x;
    int m0 = blockIdx.x * 256, n0 = blockIdx.y * 64;

    #pragma unroll
    for (int it = 0; it < 8; ++it) {         // 32 KB B tile, coalesced
        int g = it * 256 + tid;
        int row = g >> 3, c = g & 7;
        *(bf16x8*)&Bt[row][c * 8] = *(const bf16x8*)&Bbuf[(m0 + row) * E + c * 8];
    }
    #pragma unroll
    for (int it = 0; it < 2; ++it) {         // 8 KB sB tile
        int g = it * 256 + tid;
        int row = g >> 1, half = g & 1;
        *(f32x4*)&sBt[row][half * 4] = *(const f32x4*)&sB[(m0 + row) * H + half * 4];
    }

    int wave = tid >> 6, lane = tid & 63;
    int l15 = lane & 15, kq = lane >> 4;
    int nb = blockIdx.y * 4 + wave;

    bf16x8 afr[H][2];                        // fully-coalesced 1KB chunk loads
    #pragma unroll
    for (int h = 0; h < H; ++h)
        #pragma unroll
        for (int kc = 0; kc < 2; ++kc)
            afr[h][kc] = *(const bf16x8*)&AL[(((nb * 8 + h) << 1) + kc) * 512 + lane * 8];

    __syncthreads();

    int nebase = n0 + wave * 16 + kq * 4;    // C-layout row base for this lane

    #pragma unroll 2
    for (int mt = 0; mt < 16; ++mt) {
        int mrow = mt * 16 + l15;
        bf16x8 b0 = *(const bf16x8*)&Bt[mrow][kq * 8];
        bf16x8 b1 = *(const bf16x8*)&Bt[mrow][32 + kq * 8];

        f32x4 acc[H];
        #pragma unroll
        for (int h = 0; h < H; ++h) {
            acc[h] = (f32x4){0.f, 0.f, 0.f, 0.f};
            acc[h] = __builtin_amdgcn_mfma_f32_16x16x32_bf16(afr[h][0], b0, acc[h], 0, 0, 0);
            acc[h] = __builtin_amdgcn_mfma_f32_16x16x32_bf16(afr[h][1], b1, acc[h], 0, 0, 0);
        }

        float sbv[H];
        *(f32x4*)&sbv[0] = *(const f32x4*)&sBt[mrow][0];
        *(f32x4*)&sbv[4] = *(const f32x4*)&sBt[mrow][4];

        int mcol = m0 + mrow;
        bool mok = (mcol < NT);
        #pragma unroll
        for (int reg = 0; reg < 4; ++reg) {
            int ne = nebase + reg;
            float sum = 0.f;
            #pragma unroll
            for (int h = 0; h < H; ++h) {
                float tv = exp2f(acc[h][reg] * sbv[h]);       // = exp(-sim)
                sum += __builtin_amdgcn_rcpf(1.0f + tv);
            }
            if (mok && ne < NT) adj[ne * NT + mcol] = sum * 0.125f;
        }
    }
}

// ---------------------------------------------------------------- launch
extern "C" void kernel_launch(void* const* d_in, const int* in_sizes, int n_in,
                              void* d_out, int out_size, void* d_ws, size_t ws_size,
                              hipStream_t stream) {
    const float* lmX  = (const float*)d_in[0];
    const float* lmY  = (const float*)d_in[1];
    const float* tgX  = (const float*)d_in[2];
    const float* lmD  = (const float*)d_in[4];
    const float* tgD  = (const float*)d_in[5];
    const float* Wemb = (const float*)d_in[6];
    const float* bemb = (const float*)d_in[7];
    const float* w1   = (const float*)d_in[8];
    const float* w2   = (const float*)d_in[9];

    float* out   = (float*)d_out;
    float* ypred = out;                          // [N1,2]
    float* adj   = out + 4000;                   // [NT,NT]
    float* adjT  = out + 4000 + 16000000;        // [NT,NT]

    char* ws  = (char*)d_ws;
    float* sq = (float*)ws;                      //   8,000 B
    int*   idx = (int*)(ws + 8000);              //  40,000 B

    // d2 staged in adj region (consumed by k_top5 before k_adjm writes adj)
    float* d2 = adj;

    // MFMA operands staged in adjT region (overwritten by k_fillT afterwards)
    char* tz = (char*)adjT;
    unsigned short* AL   = (unsigned short*)tz;                 // 4032*8*128 B = 4,128,768
    unsigned short* Bbuf = (unsigned short*)(tz + 4128768);     // 4096*128 B   =   524,288
    float*          sB   = (float*)(tz + 4128768 + 524288);     // 4096*32 B    =   131,072

    k_sq<<<(N1 + 255) / 256, 256, 0, stream>>>(lmX, sq);
    dim3 g2(N1 / 16, N1 / 16);
    k_d2<<<g2, 256, 0, stream>>>(lmX, sq, d2);
    k_top5<<<N1, 256, 0, stream>>>(d2, lmY, ypred, idx);
    k_prep<<<NT, 64, 0, stream>>>(lmX, tgX, lmD, tgD, Wemb, bemb, w1, w2,
                                  AL, Bbuf, sB);
    dim3 ga(MPAD / 256, NPAD / 64);
    k_adjm<<<ga, 256, 0, stream>>>(AL, Bbuf, sB, adj);
    k_fillT<<<(NT * NT / 4 + 255) / 256, 256, 0, stream>>>(adjT);
    k_scatter<<<(N1 * KNN + 255) / 256, 256, 0, stream>>>(idx, adjT);
}

// Round 4
// 255.517 us; speedup vs baseline: 1.8897x; 1.2239x over previous
//
#include <hip/hip_runtime.h>
#include <math.h>

#define N1 2000
#define N2 2000
#define NT 4000
#define D  63
#define E  64
#define H  8
#define KNN 5
#define NPAD 4032   // n padded: 63 blocks of 64
#define MPAD 4096   // m padded: 16 blocks of 256

typedef short bf16x8 __attribute__((ext_vector_type(8)));
typedef float f32x4  __attribute__((ext_vector_type(4)));

__device__ __forceinline__ unsigned short f2bf(float x) {
    unsigned u = __float_as_uint(x);
    u = (u + 0x7fffu + ((u >> 16) & 1u)) >> 16;   // RN-even
    return (unsigned short)u;
}

// ---------------------------------------------------------------- k_sq
__global__ void k_sq(const float* __restrict__ X, float* __restrict__ sq) {
    int i = blockIdx.x * blockDim.x + threadIdx.x;
    if (i < N1) {
        float s = 0.f;
        for (int d = 0; d < D; ++d) { float v = X[i * D + d]; s += v * v; }
        sq[i] = s;
    }
}

// ---------------------------------------------------------------- k_d2
// 64x64 tile, 4x4 register blocking, K padded 63->64, float4 LDS (stride 68).
__global__ __launch_bounds__(256) void k_d2(const float* __restrict__ X,
                                            const float* __restrict__ sq,
                                            float* __restrict__ d2) {
    __shared__ float Xi[64][68];
    __shared__ float Xj[64][68];
    int i0 = blockIdx.y * 64, j0 = blockIdx.x * 64;
    int tid = threadIdx.x;
    for (int t = tid; t < 64 * 64; t += 256) {
        int r = t >> 6, c = t & 63;
        int gi = min(i0 + r, N1 - 1);
        int gj = min(j0 + r, N1 - 1);
        Xi[r][c] = (c < D) ? X[gi * D + c] : 0.f;
        Xj[r][c] = (c < D) ? X[gj * D + c] : 0.f;
    }
    __syncthreads();
    int tx = tid & 15, ty = tid >> 4;
    float acc[4][4];
    #pragma unroll
    for (int a = 0; a < 4; ++a)
        #pragma unroll
        for (int b = 0; b < 4; ++b) acc[a][b] = 0.f;

    #pragma unroll 4
    for (int kk = 0; kk < 16; ++kk) {
        float4 av[4], bv[4];
        #pragma unroll
        for (int ii = 0; ii < 4; ++ii) av[ii] = *(const float4*)&Xi[ty + 16 * ii][4 * kk];
        #pragma unroll
        for (int jj = 0; jj < 4; ++jj) bv[jj] = *(const float4*)&Xj[tx + 16 * jj][4 * kk];
        #pragma unroll
        for (int ii = 0; ii < 4; ++ii)
            #pragma unroll
            for (int jj = 0; jj < 4; ++jj)
                acc[ii][jj] += av[ii].x * bv[jj].x + av[ii].y * bv[jj].y +
                               av[ii].z * bv[jj].z + av[ii].w * bv[jj].w;
    }

    #pragma unroll
    for (int ii = 0; ii < 4; ++ii) {
        int i = i0 + ty + 16 * ii;
        #pragma unroll
        for (int jj = 0; jj < 4; ++jj) {
            int j = j0 + tx + 16 * jj;
            if (i < N1 && j < N1) {
                float v = sq[i] + sq[j] - 2.f * acc[ii][jj];
                if (i == j) v = __builtin_inff();
                d2[i * N1 + j] = v;
            }
        }
    }
}

// ---------------------------------------------------------------- k_top5
__device__ __forceinline__ bool dless(float d1, int i1, float d2v, int i2) {
    return d1 < d2v || (d1 == d2v && i1 < i2);   // stable top_k tie-break
}

__device__ __forceinline__ void ins5(float bd[KNN], int bi[KNN], float d, int j) {
    if (dless(d, j, bd[KNN - 1], bi[KNN - 1])) {
        bd[KNN - 1] = d; bi[KNN - 1] = j;
        #pragma unroll
        for (int s = KNN - 1; s > 0; --s) {
            if (dless(bd[s], bi[s], bd[s - 1], bi[s - 1])) {
                float td = bd[s]; bd[s] = bd[s - 1]; bd[s - 1] = td;
                int ti = bi[s]; bi[s] = bi[s - 1]; bi[s - 1] = ti;
            }
        }
    }
}

// One row per block. Lane-local top5 -> per-wave butterfly min-extract x5 ->
// 20-candidate final butterfly merge in wave 0. No serial single-thread merge.
__global__ __launch_bounds__(256) void k_top5(const float* __restrict__ d2,
                                              const float* __restrict__ lmY,
                                              float* __restrict__ ypred,
                                              int* __restrict__ idx) {
    __shared__ float sd[4 * KNN];
    __shared__ int   si[4 * KNN];
    int i = blockIdx.x;
    int tid = threadIdx.x;
    const float* row = d2 + i * N1;

    float bd[KNN]; int bi[KNN];
    #pragma unroll
    for (int s = 0; s < KNN; ++s) { bd[s] = __builtin_inff(); bi[s] = 0x7fffffff; }
    #pragma unroll
    for (int k = 0; k < 8; ++k) {
        int j = tid + k * 256;
        if (j < N1) ins5(bd, bi, row[j], j);
    }

    int lane = tid & 63, wave = tid >> 6;
    // per-wave: extract 5 global minima via butterfly
    float wd[KNN]; int wi[KNN];
    #pragma unroll
    for (int s = 0; s < KNN; ++s) {
        float d = bd[0]; int ix = bi[0];
        #pragma unroll
        for (int m = 1; m < 64; m <<= 1) {
            float od = __shfl_xor(d, m, 64);
            int   oi = __shfl_xor(ix, m, 64);
            if (dless(od, oi, d, ix)) { d = od; ix = oi; }
        }
        wd[s] = d; wi[s] = ix;
        if (d == bd[0] && ix == bi[0]) {   // unique owner pops its head
            #pragma unroll
            for (int q = 0; q < KNN - 1; ++q) { bd[q] = bd[q + 1]; bi[q] = bi[q + 1]; }
            bd[KNN - 1] = __builtin_inff(); bi[KNN - 1] = 0x7fffffff;
        }
    }
    if (lane == 0) {
        #pragma unroll
        for (int s = 0; s < KNN; ++s) { sd[wave * KNN + s] = wd[s]; si[wave * KNN + s] = wi[s]; }
    }
    __syncthreads();
    if (wave == 0) {
        float d = (lane < 4 * KNN) ? sd[lane] : __builtin_inff();
        int  ix = (lane < 4 * KNN) ? si[lane] : 0x7fffffff;
        float rd[KNN]; int ri[KNN];
        #pragma unroll
        for (int s = 0; s < KNN; ++s) {
            float md = d; int mi = ix;
            #pragma unroll
            for (int m = 1; m < 64; m <<= 1) {
                float od = __shfl_xor(md, m, 64);
                int   oi = __shfl_xor(mi, m, 64);
                if (dless(od, oi, md, mi)) { md = od; mi = oi; }
            }
            rd[s] = md; ri[s] = mi;
            if (md == d && mi == ix) { d = __builtin_inff(); ix = 0x7fffffff; }
        }
        if (lane == 0) {
            float y0 = 0.f, y1 = 0.f;
            #pragma unroll
            for (int s = 0; s < KNN; ++s) {
                int j = ri[s];
                y0 += lmY[j * 2];
                y1 += lmY[j * 2 + 1];
                idx[i * KNN + s] = j;
            }
            ypred[i * 2]     = y0 * 0.2f;
            ypred[i * 2 + 1] = y1 * 0.2f;
        }
    }
}

// ---------------------------------------------------------------- k_fillT
__global__ void k_fillT(float* __restrict__ adjT) {
    int t = blockIdx.x * blockDim.x + threadIdx.x;
    if (t < NT * NT / 4) {
        int r = (t * 4) / NT;
        int c = (t * 4) % NT;
        float v = ((r < N1) != (c < N1)) ? 1.f : 0.f;
        float4 o = {v, v, v, v};
        ((float4*)adjT)[t] = o;
    }
}

__global__ void k_scatter(const int* __restrict__ idx, float* __restrict__ adjT) {
    int t = blockIdx.x * blockDim.x + threadIdx.x;
    if (t < N1 * KNN) {
        int i = t / KNN;
        adjT[i * NT + idx[t]] = 1.f;
    }
}

// ---------------------------------------------------------------- k_prep
// Fused embedding + norms + MFMA operand build. W staged in LDS (coalesced).
__global__ __launch_bounds__(64) void k_prep(const float* __restrict__ lmX,
                                             const float* __restrict__ tgX,
                                             const float* __restrict__ lmD,
                                             const float* __restrict__ tgD,
                                             const float* __restrict__ W,
                                             const float* __restrict__ bias,
                                             const float* __restrict__ w1,
                                             const float* __restrict__ w2,
                                             unsigned short* __restrict__ AL,
                                             unsigned short* __restrict__ Bbuf,
                                             float* __restrict__ sB) {
    __shared__ float f[E];
    __shared__ float Wl[E][68];
    int n = blockIdx.x;
    int t = threadIdx.x;     // t = embedding index e, one wave
    #pragma unroll
    for (int k = 0; k < 16; ++k) {       // 1024 float4s, 16 per lane, coalesced
        int g = k * 64 + t;              // float4 index
        float4 v = ((const float4*)W)[g];
        int r = g >> 4, c = (g & 15) * 4;
        *(float4*)&Wl[r][c] = v;
    }
    if (t < D)  f[t] = (n < N1) ? lmX[n * D + t] : tgX[(n - N1) * D + t];
    if (t == D) f[t] = (n < N1) ? lmD[n] : tgD[n - N1];
    __syncthreads();
    float s0 = 0.f, s1 = 0.f, s2 = 0.f, s3 = 0.f;
    #pragma unroll
    for (int k = 0; k < 16; ++k) {
        float4 wv = *(const float4*)&Wl[t][4 * k];
        float4 fv = *(const float4*)&f[4 * k];
        s0 += fv.x * wv.x; s1 += fv.y * wv.y; s2 += fv.z * wv.z; s3 += fv.w * wv.w;
    }
    const float en = bias[t] + (s0 + s1) + (s2 + s3);
    Bbuf[n * E + t] = f2bf(en);

    int kc = t >> 5, kq = (t >> 3) & 3, j = t & 7;
    int lane = kq * 16 + (n & 15);
    int nb = n >> 4;
    #pragma unroll
    for (int h = 0; h < H; ++h) {
        float a = en * w1[t * H + h];
        float b = en * w2[t * H + h];
        float na2 = a * a, nb2 = b * b;
        #pragma unroll
        for (int m = 32; m >= 1; m >>= 1) {
            na2 += __shfl_xor(na2, m, 64);
            nb2 += __shfl_xor(nb2, m, 64);
        }
        float val = a * w2[t * H + h] * (-1.4426950408889634f) * rsqrtf(na2);
        AL[(((nb * 8 + h) << 1) + kc) * 512 + lane * 8 + j] = f2bf(val);
        if (t == h) sB[n * H + h] = rsqrtf(nb2);
    }
}

// ---------------------------------------------------------------- k_adjm
// Block: 4 waves, tile 64(n) x 256(m). B tile + sB staged in LDS (coalesced),
// A frags (8 heads x 2 k-chunks) in registers, reused over 16 m-subtiles.
__global__ __launch_bounds__(256) void k_adjm(const unsigned short* __restrict__ AL,
                                              const unsigned short* __restrict__ Bbuf,
                                              const float* __restrict__ sB,
                                              float* __restrict__ adj) {
    __shared__ unsigned short Bt[256][72];
    __shared__ float sBt[256][8];
    int tid = threadIdx.x;
    int m0 = blockIdx.x * 256, n0 = blockIdx.y * 64;

    #pragma unroll
    for (int it = 0; it < 8; ++it) {
        int g = it * 256 + tid;
        int row = g >> 3, c = g & 7;
        *(bf16x8*)&Bt[row][c * 8] = *(const bf16x8*)&Bbuf[(m0 + row) * E + c * 8];
    }
    #pragma unroll
    for (int it = 0; it < 2; ++it) {
        int g = it * 256 + tid;
        int row = g >> 1, half = g & 1;
        *(f32x4*)&sBt[row][half * 4] = *(const f32x4*)&sB[(m0 + row) * H + half * 4];
    }

    int wave = tid >> 6, lane = tid & 63;
    int l15 = lane & 15, kq = lane >> 4;
    int nb = blockIdx.y * 4 + wave;

    bf16x8 afr[H][2];
    #pragma unroll
    for (int h = 0; h < H; ++h)
        #pragma unroll
        for (int kc = 0; kc < 2; ++kc)
            afr[h][kc] = *(const bf16x8*)&AL[(((nb * 8 + h) << 1) + kc) * 512 + lane * 8];

    __syncthreads();

    int nebase = n0 + wave * 16 + kq * 4;

    #pragma unroll 2
    for (int mt = 0; mt < 16; ++mt) {
        int mrow = mt * 16 + l15;
        bf16x8 b0 = *(const bf16x8*)&Bt[mrow][kq * 8];
        bf16x8 b1 = *(const bf16x8*)&Bt[mrow][32 + kq * 8];

        f32x4 acc[H];
        #pragma unroll
        for (int h = 0; h < H; ++h) {
            acc[h] = (f32x4){0.f, 0.f, 0.f, 0.f};
            acc[h] = __builtin_amdgcn_mfma_f32_16x16x32_bf16(afr[h][0], b0, acc[h], 0, 0, 0);
            acc[h] = __builtin_amdgcn_mfma_f32_16x16x32_bf16(afr[h][1], b1, acc[h], 0, 0, 0);
        }

        float sbv[H];
        *(f32x4*)&sbv[0] = *(const f32x4*)&sBt[mrow][0];
        *(f32x4*)&sbv[4] = *(const f32x4*)&sBt[mrow][4];

        int mcol = m0 + mrow;
        bool mok = (mcol < NT);
        #pragma unroll
        for (int reg = 0; reg < 4; ++reg) {
            int ne = nebase + reg;
            float sum = 0.f;
            #pragma unroll
            for (int h = 0; h < H; ++h) {
                float tv = exp2f(acc[h][reg] * sbv[h]);       // = exp(-sim)
                sum += __builtin_amdgcn_rcpf(1.0f + tv);
            }
            if (mok && ne < NT) adj[ne * NT + mcol] = sum * 0.125f;
        }
    }
}

// ---------------------------------------------------------------- launch
extern "C" void kernel_launch(void* const* d_in, const int* in_sizes, int n_in,
                              void* d_out, int out_size, void* d_ws, size_t ws_size,
                              hipStream_t stream) {
    const float* lmX  = (const float*)d_in[0];
    const float* lmY  = (const float*)d_in[1];
    const float* tgX  = (const float*)d_in[2];
    const float* lmD  = (const float*)d_in[4];
    const float* tgD  = (const float*)d_in[5];
    const float* Wemb = (const float*)d_in[6];
    const float* bemb = (const float*)d_in[7];
    const float* w1   = (const float*)d_in[8];
    const float* w2   = (const float*)d_in[9];

    float* out   = (float*)d_out;
    float* ypred = out;                          // [N1,2]
    float* adj   = out + 4000;                   // [NT,NT]
    float* adjT  = out + 4000 + 16000000;        // [NT,NT]

    char* ws  = (char*)d_ws;
    float* sq = (float*)ws;                      //   8,000 B
    int*   idx = (int*)(ws + 8000);              //  40,000 B

    // d2 staged in adj region (consumed by k_top5 before k_adjm writes adj)
    float* d2 = adj;

    // MFMA operands staged in adjT region (overwritten by k_fillT afterwards)
    char* tz = (char*)adjT;
    unsigned short* AL   = (unsigned short*)tz;                 // 4,128,768 B
    unsigned short* Bbuf = (unsigned short*)(tz + 4128768);     //   524,288 B
    float*          sB   = (float*)(tz + 4128768 + 524288);     //   131,072 B

    k_sq<<<(N1 + 255) / 256, 256, 0, stream>>>(lmX, sq);
    dim3 g2((N1 + 63) / 64, (N1 + 63) / 64);
    k_d2<<<g2, 256, 0, stream>>>(lmX, sq, d2);
    k_top5<<<N1, 256, 0, stream>>>(d2, lmY, ypred, idx);
    k_prep<<<NT, 64, 0, stream>>>(lmX, tgX, lmD, tgD, Wemb, bemb, w1, w2,
                                  AL, Bbuf, sB);
    dim3 ga(MPAD / 256, NPAD / 64);
    k_adjm<<<ga, 256, 0, stream>>>(AL, Bbuf, sB, adj);
    k_fillT<<<(NT * NT / 4 + 255) / 256, 256, 0, stream>>>(adjT);
    k_scatter<<<(N1 * KNN + 255) / 256, 256, 0, stream>>>(idx, adjT);
}

// Round 5
// 236.711 us; speedup vs baseline: 2.0398x; 1.0794x over previous
//
#include <hip/hip_runtime.h>
#include <math.h>

#define N1 2000
#define N2 2000
#define NT 4000
#define D  63
#define E  64
#define H  8
#define KNN 5
#define NPAD 4032   // n padded: 63 blocks of 64
#define MPAD 4096   // m padded: 16 blocks of 256

typedef short bf16x8 __attribute__((ext_vector_type(8)));
typedef float f32x4  __attribute__((ext_vector_type(4)));

__device__ __forceinline__ unsigned short f2bf(float x) {
    unsigned u = __float_as_uint(x);
    u = (u + 0x7fffu + ((u >> 16) & 1u)) >> 16;   // RN-even
    return (unsigned short)u;
}

// ---------------------------------------------------------------- k_sq
__global__ void k_sq(const float* __restrict__ X, float* __restrict__ sq) {
    int i = blockIdx.x * blockDim.x + threadIdx.x;
    if (i < N1) {
        float s = 0.f;
        for (int d = 0; d < D; ++d) { float v = X[i * D + d]; s += v * v; }
        sq[i] = s;
    }
}

// ---------------------------------------------------------------- k_d2
// 64x64 tile, 4x4 register blocking, K padded 63->64, float4 LDS (stride 68).
__global__ __launch_bounds__(256) void k_d2(const float* __restrict__ X,
                                            const float* __restrict__ sq,
                                            float* __restrict__ d2) {
    __shared__ float Xi[64][68];
    __shared__ float Xj[64][68];
    int i0 = blockIdx.y * 64, j0 = blockIdx.x * 64;
    int tid = threadIdx.x;
    for (int t = tid; t < 64 * 64; t += 256) {
        int r = t >> 6, c = t & 63;
        int gi = min(i0 + r, N1 - 1);
        int gj = min(j0 + r, N1 - 1);
        Xi[r][c] = (c < D) ? X[gi * D + c] : 0.f;
        Xj[r][c] = (c < D) ? X[gj * D + c] : 0.f;
    }
    __syncthreads();
    int tx = tid & 15, ty = tid >> 4;
    float acc[4][4];
    #pragma unroll
    for (int a = 0; a < 4; ++a)
        #pragma unroll
        for (int b = 0; b < 4; ++b) acc[a][b] = 0.f;

    #pragma unroll 4
    for (int kk = 0; kk < 16; ++kk) {
        float4 av[4], bv[4];
        #pragma unroll
        for (int ii = 0; ii < 4; ++ii) av[ii] = *(const float4*)&Xi[ty + 16 * ii][4 * kk];
        #pragma unroll
        for (int jj = 0; jj < 4; ++jj) bv[jj] = *(const float4*)&Xj[tx + 16 * jj][4 * kk];
        #pragma unroll
        for (int ii = 0; ii < 4; ++ii)
            #pragma unroll
            for (int jj = 0; jj < 4; ++jj)
                acc[ii][jj] += av[ii].x * bv[jj].x + av[ii].y * bv[jj].y +
                               av[ii].z * bv[jj].z + av[ii].w * bv[jj].w;
    }

    #pragma unroll
    for (int ii = 0; ii < 4; ++ii) {
        int i = i0 + ty + 16 * ii;
        #pragma unroll
        for (int jj = 0; jj < 4; ++jj) {
            int j = j0 + tx + 16 * jj;
            if (i < N1 && j < N1) {
                float v = sq[i] + sq[j] - 2.f * acc[ii][jj];
                if (i == j) v = __builtin_inff();
                d2[i * N1 + j] = v;
            }
        }
    }
}

// ---------------------------------------------------------------- k_top5
__device__ __forceinline__ bool dless(float d1, int i1, float d2v, int i2) {
    return d1 < d2v || (d1 == d2v && i1 < i2);   // stable top_k tie-break
}

__device__ __forceinline__ void ins5(float bd[KNN], int bi[KNN], float d, int j) {
    if (dless(d, j, bd[KNN - 1], bi[KNN - 1])) {
        bd[KNN - 1] = d; bi[KNN - 1] = j;
        #pragma unroll
        for (int s = KNN - 1; s > 0; --s) {
            if (dless(bd[s], bi[s], bd[s - 1], bi[s - 1])) {
                float td = bd[s]; bd[s] = bd[s - 1]; bd[s - 1] = td;
                int ti = bi[s]; bi[s] = bi[s - 1]; bi[s - 1] = ti;
            }
        }
    }
}

// One row per block. Lane-local top5 -> per-wave butterfly min-extract x5 ->
// 20-candidate final butterfly merge in wave 0.
__global__ __launch_bounds__(256) void k_top5(const float* __restrict__ d2,
                                              const float* __restrict__ lmY,
                                              float* __restrict__ ypred,
                                              int* __restrict__ idx) {
    __shared__ float sd[4 * KNN];
    __shared__ int   si[4 * KNN];
    int i = blockIdx.x;
    int tid = threadIdx.x;
    const float* row = d2 + i * N1;

    float bd[KNN]; int bi[KNN];
    #pragma unroll
    for (int s = 0; s < KNN; ++s) { bd[s] = __builtin_inff(); bi[s] = 0x7fffffff; }
    #pragma unroll
    for (int k = 0; k < 8; ++k) {
        int j = tid + k * 256;
        if (j < N1) ins5(bd, bi, row[j], j);
    }

    int lane = tid & 63, wave = tid >> 6;
    float wd[KNN]; int wi[KNN];
    #pragma unroll
    for (int s = 0; s < KNN; ++s) {
        float d = bd[0]; int ix = bi[0];
        #pragma unroll
        for (int m = 1; m < 64; m <<= 1) {
            float od = __shfl_xor(d, m, 64);
            int   oi = __shfl_xor(ix, m, 64);
            if (dless(od, oi, d, ix)) { d = od; ix = oi; }
        }
        wd[s] = d; wi[s] = ix;
        if (d == bd[0] && ix == bi[0]) {
            #pragma unroll
            for (int q = 0; q < KNN - 1; ++q) { bd[q] = bd[q + 1]; bi[q] = bi[q + 1]; }
            bd[KNN - 1] = __builtin_inff(); bi[KNN - 1] = 0x7fffffff;
        }
    }
    if (lane == 0) {
        #pragma unroll
        for (int s = 0; s < KNN; ++s) { sd[wave * KNN + s] = wd[s]; si[wave * KNN + s] = wi[s]; }
    }
    __syncthreads();
    if (wave == 0) {
        float d = (lane < 4 * KNN) ? sd[lane] : __builtin_inff();
        int  ix = (lane < 4 * KNN) ? si[lane] : 0x7fffffff;
        float rd[KNN]; int ri[KNN];
        #pragma unroll
        for (int s = 0; s < KNN; ++s) {
            float md = d; int mi = ix;
            #pragma unroll
            for (int m = 1; m < 64; m <<= 1) {
                float od = __shfl_xor(md, m, 64);
                int   oi = __shfl_xor(mi, m, 64);
                if (dless(od, oi, md, mi)) { md = od; mi = oi; }
            }
            rd[s] = md; ri[s] = mi;
            if (md == d && mi == ix) { d = __builtin_inff(); ix = 0x7fffffff; }
        }
        if (lane == 0) {
            float y0 = 0.f, y1 = 0.f;
            #pragma unroll
            for (int s = 0; s < KNN; ++s) {
                int j = ri[s];
                y0 += lmY[j * 2];
                y1 += lmY[j * 2 + 1];
                idx[i * KNN + s] = j;
            }
            ypred[i * 2]     = y0 * 0.2f;
            ypred[i * 2 + 1] = y1 * 0.2f;
        }
    }
}

// ---------------------------------------------------------------- k_fillT
__global__ void k_fillT(float* __restrict__ adjT) {
    int t = blockIdx.x * blockDim.x + threadIdx.x;
    if (t < NT * NT / 4) {
        int r = (t * 4) / NT;
        int c = (t * 4) % NT;
        float v = ((r < N1) != (c < N1)) ? 1.f : 0.f;
        float4 o = {v, v, v, v};
        ((float4*)adjT)[t] = o;
    }
}

__global__ void k_scatter(const int* __restrict__ idx, float* __restrict__ adjT) {
    int t = blockIdx.x * blockDim.x + threadIdx.x;
    if (t < N1 * KNN) {
        int i = t / KNN;
        adjT[i * NT + idx[t]] = 1.f;
    }
}

// ---------------------------------------------------------------- k_prep
// Fused embedding + norms + MFMA operand build. W staged in LDS (coalesced).
// AL fold is now +1/||a|| (raw sim needed by the polynomial sigmoid).
__global__ __launch_bounds__(64) void k_prep(const float* __restrict__ lmX,
                                             const float* __restrict__ tgX,
                                             const float* __restrict__ lmD,
                                             const float* __restrict__ tgD,
                                             const float* __restrict__ W,
                                             const float* __restrict__ bias,
                                             const float* __restrict__ w1,
                                             const float* __restrict__ w2,
                                             unsigned short* __restrict__ AL,
                                             unsigned short* __restrict__ Bbuf,
                                             float* __restrict__ sB) {
    __shared__ float f[E];
    __shared__ float Wl[E][68];
    int n = blockIdx.x;
    int t = threadIdx.x;
    #pragma unroll
    for (int k = 0; k < 16; ++k) {
        int g = k * 64 + t;
        float4 v = ((const float4*)W)[g];
        int r = g >> 4, c = (g & 15) * 4;
        *(float4*)&Wl[r][c] = v;
    }
    if (t < D)  f[t] = (n < N1) ? lmX[n * D + t] : tgX[(n - N1) * D + t];
    if (t == D) f[t] = (n < N1) ? lmD[n] : tgD[n - N1];
    __syncthreads();
    float s0 = 0.f, s1 = 0.f, s2 = 0.f, s3 = 0.f;
    #pragma unroll
    for (int k = 0; k < 16; ++k) {
        float4 wv = *(const float4*)&Wl[t][4 * k];
        float4 fv = *(const float4*)&f[4 * k];
        s0 += fv.x * wv.x; s1 += fv.y * wv.y; s2 += fv.z * wv.z; s3 += fv.w * wv.w;
    }
    const float en = bias[t] + (s0 + s1) + (s2 + s3);
    Bbuf[n * E + t] = f2bf(en);

    int kc = t >> 5, kq = (t >> 3) & 3, j = t & 7;
    int lane = kq * 16 + (n & 15);
    int nb = n >> 4;
    #pragma unroll
    for (int h = 0; h < H; ++h) {
        float a = en * w1[t * H + h];
        float b = en * w2[t * H + h];
        float na2 = a * a, nb2 = b * b;
        #pragma unroll
        for (int m = 32; m >= 1; m >>= 1) {
            na2 += __shfl_xor(na2, m, 64);
            nb2 += __shfl_xor(nb2, m, 64);
        }
        float val = a * w2[t * H + h] * rsqrtf(na2);   // folds 1/||a||
        AL[(((nb * 8 + h) << 1) + kc) * 512 + lane * 8 + j] = f2bf(val);
        if (t == h) sB[n * H + h] = rsqrtf(nb2);
    }
}

// ---------------------------------------------------------------- k_adjm
// Block: 4 waves, tile 64(n) x 256(m). B tile in LDS (pad 68: 2-way = free),
// A frags in registers (reused over 16 m-subtiles), sB via L1-hot global.
// Epilogue: polynomial sigmoid (sim in [-1,1]) -- zero transcendentals.
//   sigma(x) ~= 0.5 + x*(0.25 + u*(-1/48 + u*1.8919e-3)), u=x^2, |err|<=5e-5
__global__ __launch_bounds__(256) void k_adjm(const unsigned short* __restrict__ AL,
                                              const unsigned short* __restrict__ Bbuf,
                                              const float* __restrict__ sB,
                                              float* __restrict__ adj) {
    __shared__ unsigned short Bt[256][68];   // 34,816 B -> 4 blocks/CU
    int tid = threadIdx.x;
    int m0 = blockIdx.x * 256, n0 = blockIdx.y * 64;

    #pragma unroll
    for (int it = 0; it < 8; ++it) {
        int g = it * 256 + tid;
        int row = g >> 3, c = g & 7;
        *(bf16x8*)&Bt[row][c * 8] = *(const bf16x8*)&Bbuf[(m0 + row) * E + c * 8];
    }

    int wave = tid >> 6, lane = tid & 63;
    int l15 = lane & 15, kq = lane >> 4;
    int nb = blockIdx.y * 4 + wave;

    bf16x8 afr[H][2];
    #pragma unroll
    for (int h = 0; h < H; ++h)
        #pragma unroll
        for (int kc = 0; kc < 2; ++kc)
            afr[h][kc] = *(const bf16x8*)&AL[(((nb * 8 + h) << 1) + kc) * 512 + lane * 8];

    __syncthreads();

    int nebase = n0 + wave * 16 + kq * 4;

    #pragma unroll 2
    for (int mt = 0; mt < 16; ++mt) {
        int mrow = mt * 16 + l15;
        int mcol = m0 + mrow;
        bf16x8 b0 = *(const bf16x8*)&Bt[mrow][kq * 8];
        bf16x8 b1 = *(const bf16x8*)&Bt[mrow][32 + kq * 8];

        float sbv[H];
        *(f32x4*)&sbv[0] = *(const f32x4*)&sB[mcol * H + 0];
        *(f32x4*)&sbv[4] = *(const f32x4*)&sB[mcol * H + 4];

        f32x4 acc[H];
        #pragma unroll
        for (int h = 0; h < H; ++h) {
            acc[h] = (f32x4){0.f, 0.f, 0.f, 0.f};
            acc[h] = __builtin_amdgcn_mfma_f32_16x16x32_bf16(afr[h][0], b0, acc[h], 0, 0, 0);
            acc[h] = __builtin_amdgcn_mfma_f32_16x16x32_bf16(afr[h][1], b1, acc[h], 0, 0, 0);
        }

        bool mok = (mcol < NT);
        #pragma unroll
        for (int reg = 0; reg < 4; ++reg) {
            int ne = nebase + reg;
            float sum = 0.f;
            #pragma unroll
            for (int h = 0; h < H; ++h) {
                float x = acc[h][reg] * sbv[h];               // sim, in [-1,1]
                float u = x * x;
                float p = fmaf(u, 1.8919e-3f, -2.0833333e-2f);
                p = fmaf(u, p, 0.25f);
                sum = fmaf(x, p, sum);                        // += sigma(x)-0.5
            }
            if (mok && ne < NT) adj[ne * NT + mcol] = fmaf(sum, 0.125f, 0.5f);
        }
    }
}

// ---------------------------------------------------------------- launch
extern "C" void kernel_launch(void* const* d_in, const int* in_sizes, int n_in,
                              void* d_out, int out_size, void* d_ws, size_t ws_size,
                              hipStream_t stream) {
    const float* lmX  = (const float*)d_in[0];
    const float* lmY  = (const float*)d_in[1];
    const float* tgX  = (const float*)d_in[2];
    const float* lmD  = (const float*)d_in[4];
    const float* tgD  = (const float*)d_in[5];
    const float* Wemb = (const float*)d_in[6];
    const float* bemb = (const float*)d_in[7];
    const float* w1   = (const float*)d_in[8];
    const float* w2   = (const float*)d_in[9];

    float* out   = (float*)d_out;
    float* ypred = out;                          // [N1,2]
    float* adj   = out + 4000;                   // [NT,NT]
    float* adjT  = out + 4000 + 16000000;        // [NT,NT]

    char* ws  = (char*)d_ws;
    float* sq = (float*)ws;                      //   8,000 B
    int*   idx = (int*)(ws + 8000);              //  40,000 B

    // d2 staged in adj region (consumed by k_top5 before k_adjm writes adj)
    float* d2 = adj;

    // MFMA operands staged in adjT region (overwritten by k_fillT afterwards)
    char* tz = (char*)adjT;
    unsigned short* AL   = (unsigned short*)tz;                 // 4,128,768 B
    unsigned short* Bbuf = (unsigned short*)(tz + 4128768);     //   524,288 B
    float*          sB   = (float*)(tz + 4128768 + 524288);     //   131,072 B

    k_sq<<<(N1 + 255) / 256, 256, 0, stream>>>(lmX, sq);
    dim3 g2((N1 + 63) / 64, (N1 + 63) / 64);
    k_d2<<<g2, 256, 0, stream>>>(lmX, sq, d2);
    k_top5<<<N1, 256, 0, stream>>>(d2, lmY, ypred, idx);
    k_prep<<<NT, 64, 0, stream>>>(lmX, tgX, lmD, tgD, Wemb, bemb, w1, w2,
                                  AL, Bbuf, sB);
    dim3 ga(MPAD / 256, NPAD / 64);
    k_adjm<<<ga, 256, 0, stream>>>(AL, Bbuf, sB, adj);
    k_fillT<<<(NT * NT / 4 + 255) / 256, 256, 0, stream>>>(adjT);
    k_scatter<<<(N1 * KNN + 255) / 256, 256, 0, stream>>>(idx, adjT);
}

// Round 6
// 226.041 us; speedup vs baseline: 2.1361x; 1.0472x over previous
//
#include <hip/hip_runtime.h>
#include <math.h>

#define N1 2000
#define N2 2000
#define NT 4000
#define D  63
#define E  64
#define H  8
#define KNN 5
#define NPAD 4032   // n padded: 63 blocks of 64
#define MPAD 4096   // m padded: 16 blocks of 256

typedef short bf16x8 __attribute__((ext_vector_type(8)));
typedef float f32x4  __attribute__((ext_vector_type(4)));

__device__ __forceinline__ unsigned short f2bf(float x) {
    unsigned u = __float_as_uint(x);
    u = (u + 0x7fffu + ((u >> 16) & 1u)) >> 16;   // RN-even
    return (unsigned short)u;
}

// ---------------------------------------------------------------- k_sq
__global__ void k_sq(const float* __restrict__ X, float* __restrict__ sq) {
    int i = blockIdx.x * blockDim.x + threadIdx.x;
    if (i < N1) {
        float s = 0.f;
        for (int d = 0; d < D; ++d) { float v = X[i * D + d]; s += v * v; }
        sq[i] = s;
    }
}

// ---------------------------------------------------------------- k_d2
// 64x64 tile, 4x4 register blocking, K padded 63->64, float4 LDS (stride 68).
__global__ __launch_bounds__(256) void k_d2(const float* __restrict__ X,
                                            const float* __restrict__ sq,
                                            float* __restrict__ d2) {
    __shared__ float Xi[64][68];
    __shared__ float Xj[64][68];
    int i0 = blockIdx.y * 64, j0 = blockIdx.x * 64;
    int tid = threadIdx.x;
    for (int t = tid; t < 64 * 64; t += 256) {
        int r = t >> 6, c = t & 63;
        int gi = min(i0 + r, N1 - 1);
        int gj = min(j0 + r, N1 - 1);
        Xi[r][c] = (c < D) ? X[gi * D + c] : 0.f;
        Xj[r][c] = (c < D) ? X[gj * D + c] : 0.f;
    }
    __syncthreads();
    int tx = tid & 15, ty = tid >> 4;
    float acc[4][4];
    #pragma unroll
    for (int a = 0; a < 4; ++a)
        #pragma unroll
        for (int b = 0; b < 4; ++b) acc[a][b] = 0.f;

    #pragma unroll 4
    for (int kk = 0; kk < 16; ++kk) {
        float4 av[4], bv[4];
        #pragma unroll
        for (int ii = 0; ii < 4; ++ii) av[ii] = *(const float4*)&Xi[ty + 16 * ii][4 * kk];
        #pragma unroll
        for (int jj = 0; jj < 4; ++jj) bv[jj] = *(const float4*)&Xj[tx + 16 * jj][4 * kk];
        #pragma unroll
        for (int ii = 0; ii < 4; ++ii)
            #pragma unroll
            for (int jj = 0; jj < 4; ++jj)
                acc[ii][jj] += av[ii].x * bv[jj].x + av[ii].y * bv[jj].y +
                               av[ii].z * bv[jj].z + av[ii].w * bv[jj].w;
    }

    #pragma unroll
    for (int ii = 0; ii < 4; ++ii) {
        int i = i0 + ty + 16 * ii;
        #pragma unroll
        for (int jj = 0; jj < 4; ++jj) {
            int j = j0 + tx + 16 * jj;
            if (i < N1 && j < N1) {
                float v = sq[i] + sq[j] - 2.f * acc[ii][jj];
                if (i == j) v = __builtin_inff();
                d2[i * N1 + j] = v;
            }
        }
    }
}

// ---------------------------------------------------------------- k_top5
__device__ __forceinline__ bool dless(float d1, int i1, float d2v, int i2) {
    return d1 < d2v || (d1 == d2v && i1 < i2);   // stable top_k tie-break
}

__device__ __forceinline__ void ins5(float bd[KNN], int bi[KNN], float d, int j) {
    if (dless(d, j, bd[KNN - 1], bi[KNN - 1])) {
        bd[KNN - 1] = d; bi[KNN - 1] = j;
        #pragma unroll
        for (int s = KNN - 1; s > 0; --s) {
            if (dless(bd[s], bi[s], bd[s - 1], bi[s - 1])) {
                float td = bd[s]; bd[s] = bd[s - 1]; bd[s - 1] = td;
                int ti = bi[s]; bi[s] = bi[s - 1]; bi[s - 1] = ti;
            }
        }
    }
}

// One row per block. Lane-local top5 -> per-wave butterfly min-extract x5 ->
// 20-candidate final butterfly merge in wave 0.
__global__ __launch_bounds__(256) void k_top5(const float* __restrict__ d2,
                                              const float* __restrict__ lmY,
                                              float* __restrict__ ypred,
                                              int* __restrict__ idx) {
    __shared__ float sd[4 * KNN];
    __shared__ int   si[4 * KNN];
    int i = blockIdx.x;
    int tid = threadIdx.x;
    const float* row = d2 + i * N1;

    float bd[KNN]; int bi[KNN];
    #pragma unroll
    for (int s = 0; s < KNN; ++s) { bd[s] = __builtin_inff(); bi[s] = 0x7fffffff; }
    #pragma unroll
    for (int k = 0; k < 8; ++k) {
        int j = tid + k * 256;
        if (j < N1) ins5(bd, bi, row[j], j);
    }

    int lane = tid & 63, wave = tid >> 6;
    float wd[KNN]; int wi[KNN];
    #pragma unroll
    for (int s = 0; s < KNN; ++s) {
        float d = bd[0]; int ix = bi[0];
        #pragma unroll
        for (int m = 1; m < 64; m <<= 1) {
            float od = __shfl_xor(d, m, 64);
            int   oi = __shfl_xor(ix, m, 64);
            if (dless(od, oi, d, ix)) { d = od; ix = oi; }
        }
        wd[s] = d; wi[s] = ix;
        if (d == bd[0] && ix == bi[0]) {
            #pragma unroll
            for (int q = 0; q < KNN - 1; ++q) { bd[q] = bd[q + 1]; bi[q] = bi[q + 1]; }
            bd[KNN - 1] = __builtin_inff(); bi[KNN - 1] = 0x7fffffff;
        }
    }
    if (lane == 0) {
        #pragma unroll
        for (int s = 0; s < KNN; ++s) { sd[wave * KNN + s] = wd[s]; si[wave * KNN + s] = wi[s]; }
    }
    __syncthreads();
    if (wave == 0) {
        float d = (lane < 4 * KNN) ? sd[lane] : __builtin_inff();
        int  ix = (lane < 4 * KNN) ? si[lane] : 0x7fffffff;
        float rd[KNN]; int ri[KNN];
        #pragma unroll
        for (int s = 0; s < KNN; ++s) {
            float md = d; int mi = ix;
            #pragma unroll
            for (int m = 1; m < 64; m <<= 1) {
                float od = __shfl_xor(md, m, 64);
                int   oi = __shfl_xor(mi, m, 64);
                if (dless(od, oi, md, mi)) { md = od; mi = oi; }
            }
            rd[s] = md; ri[s] = mi;
            if (md == d && mi == ix) { d = __builtin_inff(); ix = 0x7fffffff; }
        }
        if (lane == 0) {
            float y0 = 0.f, y1 = 0.f;
            #pragma unroll
            for (int s = 0; s < KNN; ++s) {
                int j = ri[s];
                y0 += lmY[j * 2];
                y1 += lmY[j * 2 + 1];
                idx[i * KNN + s] = j;
            }
            ypred[i * 2]     = y0 * 0.2f;
            ypred[i * 2 + 1] = y1 * 0.2f;
        }
    }
}

// ---------------------------------------------------------------- k_prep
// 4 nodes per block (1 per wave); W_emb staged in LDS once per block.
// AL fold: +1/||a||. Bbuf = bf16(e). sB = 1/||b||.
__global__ __launch_bounds__(256) void k_prep(const float* __restrict__ lmX,
                                              const float* __restrict__ tgX,
                                              const float* __restrict__ lmD,
                                              const float* __restrict__ tgD,
                                              const float* __restrict__ W,
                                              const float* __restrict__ bias,
                                              const float* __restrict__ w1,
                                              const float* __restrict__ w2,
                                              unsigned short* __restrict__ AL,
                                              unsigned short* __restrict__ Bbuf,
                                              float* __restrict__ sB) {
    __shared__ float f[4][E];
    __shared__ float Wl[E][68];
    int tid = threadIdx.x, lane = tid & 63, wave = tid >> 6;
    int n = blockIdx.x * 4 + wave;       // grid = 1000 -> n < 4000
    #pragma unroll
    for (int k = 0; k < 4; ++k) {        // 1024 float4s, 4/thread, coalesced
        int g = k * 256 + tid;
        float4 v = ((const float4*)W)[g];
        int r = g >> 4, c = (g & 15) * 4;
        *(float4*)&Wl[r][c] = v;
    }
    int t = lane;
    if (t < D)  f[wave][t] = (n < N1) ? lmX[n * D + t] : tgX[(n - N1) * D + t];
    if (t == D) f[wave][t] = (n < N1) ? lmD[n] : tgD[n - N1];
    __syncthreads();
    float s0 = 0.f, s1 = 0.f, s2 = 0.f, s3 = 0.f;
    #pragma unroll
    for (int k = 0; k < 16; ++k) {
        float4 wv = *(const float4*)&Wl[t][4 * k];
        float4 fv = *(const float4*)&f[wave][4 * k];
        s0 += fv.x * wv.x; s1 += fv.y * wv.y; s2 += fv.z * wv.z; s3 += fv.w * wv.w;
    }
    const float en = bias[t] + (s0 + s1) + (s2 + s3);
    Bbuf[n * E + t] = f2bf(en);

    int kc = t >> 5, kq = (t >> 3) & 3, j = t & 7;
    int alane = kq * 16 + (n & 15);
    int nb = n >> 4;
    #pragma unroll
    for (int h = 0; h < H; ++h) {
        float a = en * w1[t * H + h];
        float b = en * w2[t * H + h];
        float na2 = a * a, nb2 = b * b;
        #pragma unroll
        for (int m = 32; m >= 1; m >>= 1) {
            na2 += __shfl_xor(na2, m, 64);
            nb2 += __shfl_xor(nb2, m, 64);
        }
        float val = a * w2[t * H + h] * rsqrtf(na2);   // folds 1/||a||
        AL[(((nb * 8 + h) << 1) + kc) * 512 + alane * 8 + j] = f2bf(val);
        if (t == h) sB[n * H + h] = rsqrtf(nb2);
    }
}

// ---------------------------------------------------------------- k_adjm
// Block: 4 waves, tile 64(n) x 256(m). B tile in LDS, A frags in registers.
// Polynomial sigmoid epilogue (sim in [-1,1], |err|<=5e-5).
// FUSED: also writes this block's 64x256 adj_teacher tile (pattern + KNN
// scatter for lm rows) -- overlaps the adjT store stream with compute.
__global__ __launch_bounds__(256) void k_adjm(const unsigned short* __restrict__ AL,
                                              const unsigned short* __restrict__ Bbuf,
                                              const float* __restrict__ sB,
                                              const int* __restrict__ idx,
                                              float* __restrict__ adj,
                                              float* __restrict__ adjT) {
    __shared__ unsigned short Bt[256][68];   // 34,816 B -> 4 blocks/CU
    int tid = threadIdx.x;
    int m0 = blockIdx.x * 256, n0 = blockIdx.y * 64;

    #pragma unroll
    for (int it = 0; it < 8; ++it) {
        int g = it * 256 + tid;
        int row = g >> 3, c = g & 7;
        *(bf16x8*)&Bt[row][c * 8] = *(const bf16x8*)&Bbuf[(m0 + row) * E + c * 8];
    }

    int wave = tid >> 6, lane = tid & 63;
    int l15 = lane & 15, kq = lane >> 4;
    int nb = blockIdx.y * 4 + wave;

    bf16x8 afr[H][2];
    #pragma unroll
    for (int h = 0; h < H; ++h)
        #pragma unroll
        for (int kc = 0; kc < 2; ++kc)
            afr[h][kc] = *(const bf16x8*)&AL[(((nb * 8 + h) << 1) + kc) * 512 + lane * 8];

    __syncthreads();

    int nebase = n0 + wave * 16 + kq * 4;

    #pragma unroll 2
    for (int mt = 0; mt < 16; ++mt) {
        int mrow = mt * 16 + l15;
        int mcol = m0 + mrow;
        bf16x8 b0 = *(const bf16x8*)&Bt[mrow][kq * 8];
        bf16x8 b1 = *(const bf16x8*)&Bt[mrow][32 + kq * 8];

        float sbv[H];
        *(f32x4*)&sbv[0] = *(const f32x4*)&sB[mcol * H + 0];
        *(f32x4*)&sbv[4] = *(const f32x4*)&sB[mcol * H + 4];

        f32x4 acc[H];
        #pragma unroll
        for (int h = 0; h < H; ++h) {
            acc[h] = (f32x4){0.f, 0.f, 0.f, 0.f};
            acc[h] = __builtin_amdgcn_mfma_f32_16x16x32_bf16(afr[h][0], b0, acc[h], 0, 0, 0);
            acc[h] = __builtin_amdgcn_mfma_f32_16x16x32_bf16(afr[h][1], b1, acc[h], 0, 0, 0);
        }

        bool mok = (mcol < NT);
        #pragma unroll
        for (int reg = 0; reg < 4; ++reg) {
            int ne = nebase + reg;
            float sum = 0.f;
            #pragma unroll
            for (int h = 0; h < H; ++h) {
                float x = acc[h][reg] * sbv[h];               // sim, in [-1,1]
                float u = x * x;
                float p = fmaf(u, 1.8919e-3f, -2.0833333e-2f);
                p = fmaf(u, p, 0.25f);
                sum = fmaf(x, p, sum);                        // += sigma(x)-0.5
            }
            if (mok && ne < NT) adj[ne * NT + mcol] = fmaf(sum, 0.125f, 0.5f);
        }
    }

    // ---- adj_teacher tile: base pattern (disjoint across blocks) ----
    #pragma unroll
    for (int it = 0; it < 16; ++it) {            // 4096 float4s / 256 thr
        int g = it * 256 + tid;
        int r = g >> 6;                          // 64 float4s per row
        int col = m0 + (g & 63) * 4;
        int row = n0 + r;
        if (row < NT && col < NT) {
            float v = ((row < N1) != (col < N1)) ? 1.f : 0.f;
            float4 o = {v, v, v, v};
            *(float4*)&adjT[row * NT + col] = o;
        }
    }
    __syncthreads();                             // order scatter after fill
    // ---- KNN scatter: rows n0..n0+63 (lm only), cols within this tile ----
    for (int p = tid; p < 64 * KNN; p += 256) {
        int r = p / KNN, s = p - r * KNN;
        int row = n0 + r;
        if (row < N1) {
            int jx = idx[row * KNN + s];
            if (jx >= m0 && jx < m0 + 256) adjT[row * NT + jx] = 1.f;
        }
    }
}

// ---------------------------------------------------------------- launch
extern "C" void kernel_launch(void* const* d_in, const int* in_sizes, int n_in,
                              void* d_out, int out_size, void* d_ws, size_t ws_size,
                              hipStream_t stream) {
    const float* lmX  = (const float*)d_in[0];
    const float* lmY  = (const float*)d_in[1];
    const float* tgX  = (const float*)d_in[2];
    const float* lmD  = (const float*)d_in[4];
    const float* tgD  = (const float*)d_in[5];
    const float* Wemb = (const float*)d_in[6];
    const float* bemb = (const float*)d_in[7];
    const float* w1   = (const float*)d_in[8];
    const float* w2   = (const float*)d_in[9];

    float* out   = (float*)d_out;
    float* ypred = out;                          // [N1,2]
    float* adj   = out + 4000;                   // [NT,NT]
    float* adjT  = out + 4000 + 16000000;        // [NT,NT]

    // scratch layout in d_ws (~4.84 MB; ws is ~372 MB per poison size)
    char* ws = (char*)d_ws;
    unsigned short* AL   = (unsigned short*)ws;                  // 4,128,768 B
    unsigned short* Bbuf = (unsigned short*)(ws + 4128768);      //   524,288 B
    float*          sB   = (float*)(ws + 4128768 + 524288);      //   131,072 B
    float*          sq   = (float*)(ws + 4784128);               //     8,000 B
    int*            idx  = (int*)  (ws + 4792128);               //    40,000 B

    // d2 staged in adj region (consumed by k_top5 before k_adjm writes adj)
    float* d2 = adj;

    k_sq<<<(N1 + 255) / 256, 256, 0, stream>>>(lmX, sq);
    dim3 g2((N1 + 63) / 64, (N1 + 63) / 64);
    k_d2<<<g2, 256, 0, stream>>>(lmX, sq, d2);
    k_top5<<<N1, 256, 0, stream>>>(d2, lmY, ypred, idx);
    k_prep<<<NT / 4, 256, 0, stream>>>(lmX, tgX, lmD, tgD, Wemb, bemb, w1, w2,
                                       AL, Bbuf, sB);
    dim3 ga(MPAD / 256, NPAD / 64);
    k_adjm<<<ga, 256, 0, stream>>>(AL, Bbuf, sB, idx, adj, adjT);
}